// Round 3
// baseline (1917.034 us; speedup 1.0000x reference)
//
#include <hip/hip_runtime.h>

namespace {

constexpr int B = 64;
constexpr int L = 2048;
constexpr int Q = 256;
constexpr int S = 26;
constexpr float EPS = 1e-16f;
constexpr size_t POST = (size_t)B * L * Q;  // loglik offset in d_out

typedef _Float16 f16x8 __attribute__((ext_vector_type(8)));
typedef float f32x4 __attribute__((ext_vector_type(4)));

#define MFMA16(a, b, c) __builtin_amdgcn_mfma_f32_16x16x32_f16((a), (b), (c), 0, 0, 0)

struct Smem {
  alignas(16) _Float16 vb[2][Q];  // scaled linear recursion vector (f16), dbuf
  float sh[2];                    // state-0 anchor broadcast, dbuf
  alignas(16) float afin[Q];      // final alpha for exact loglik
};

// LDS-only rendezvous: raw s_barrier with lgkm drain only. No vmcnt drain, so
// global loads/stores stay in flight across steps. sched_barrier(0) guards
// against scheduler motion of ds ops across the asm (guide rule #18).
__device__ __forceinline__ void lds_barrier() {
  __builtin_amdgcn_sched_barrier(0);
  asm volatile("s_waitcnt lgkmcnt(0)");
  __builtin_amdgcn_s_barrier();
  __builtin_amdgcn_sched_barrier(0);
}

__device__ __forceinline__ float wave_max64(float x) {
#pragma unroll
  for (int off = 32; off > 0; off >>= 1) x = fmaxf(x, __shfl_xor(x, off, 64));
  return x;
}
__device__ __forceinline__ float wave_sum64(float x) {
#pragma unroll
  for (int off = 32; off > 0; off >>= 1) x += __shfl_xor(x, off, 64);
  return x;
}

// Per-lane slice (8 floats as 4x float2, always 8B-aligned since row stride
// 104B) of one input row. Only A-row-0 lanes (lane&15==0) participate.
// g==3 covers s=24..31: only 24,25 exist; ld[1..3] stay zero (never loads OOB).
__device__ __forceinline__ void load_row(const float2* __restrict__ r2, int g,
                                         bool rdl, float2* ld) {
  if (rdl) {
    const float2* p = r2 + g * 4;
    ld[0] = p[0];
    if (g < 3) { ld[1] = p[1]; ld[2] = p[2]; ld[3] = p[3]; }
  }
}

// Convert a row slice to hi/lo f16 A-frags (all lanes; non-participating
// lanes hold zeros, harmless for the D-row-0 trick).
__device__ __forceinline__ void cvt_row(const float2* ld, f16x8& xh, f16x8& xl) {
#pragma unroll
  for (int i = 0; i < 4; ++i) {
    const float a = ld[i].x, bb = ld[i].y;
    const _Float16 ah = (_Float16)a, bh = (_Float16)bb;
    xh[2 * i] = ah;     xl[2 * i] = (_Float16)(a - (float)ah);
    xh[2 * i + 1] = bh; xl[2 * i + 1] = (_Float16)(bb - (float)bh);
  }
}

// emit_k = (xh+xl).(Bh+Bl) ~= xh*Bl + xl*Bh + xh*Bh per 16-state tile k.
// Returns e[k] = E[0] + EPS (D row 0, lanes 0..15).
__device__ __forceinline__ void emit4(const f16x8& xh, const f16x8& xl,
                                      const f16x8* Bh, const f16x8* Bl, float* e) {
  const f32x4 Z = {0.f, 0.f, 0.f, 0.f};
#pragma unroll
  for (int k = 0; k < 4; ++k) {
    f32x4 E = MFMA16(xh, Bl[k], Z);
    E = MFMA16(xl, Bh[k], E);
    E = MFMA16(xh, Bh[k], E);
    e[k] = E[0] + EPS;
  }
}

// x_k = v^T * T_k for this wave's four 16-state column tiles; K=256 as 8
// frags, two 4-deep chains per tile (8 independent chains total). Only D row
// 0 is meaningful; garbage in A rows 1..15 cannot reach row 0.
__device__ __forceinline__ void matvec4(const f16x8* va, const f16x8 (*T)[8],
                                        float* x) {
  const f32x4 Z = {0.f, 0.f, 0.f, 0.f};
#pragma unroll
  for (int k = 0; k < 4; ++k) {
    f32x4 Xa = MFMA16(va[0], T[k][0], Z);
    f32x4 Xb = MFMA16(va[4], T[k][4], Z);
#pragma unroll
    for (int f = 1; f < 4; ++f) {
      Xa = MFMA16(va[f], T[k][f], Xa);
      Xb = MFMA16(va[f + 4], T[k][f + 4], Xb);
    }
    x[k] = Xa[0] + Xb[0];
  }
}

// Sparse frag reads: 4 active lanes read 16B each from one contiguous 64B
// block per instruction; 8 instructions cover the full 256-f16 vector.
__device__ __forceinline__ void read_frags(Smem& sm, int p, int g, f16x8* va) {
  const _Float16* vbp = sm.vb[p];
#pragma unroll
  for (int f = 0; f < 8; ++f) va[f] = *(const f16x8*)(vbp + f * 32 + g * 8);
}

// ---------------- forward ----------------
// 4 waves x 64 states. Linear-space recursion with one-step-stale state-0
// anchor (identical math to the verified R1/R2 kernels).
__device__ __forceinline__ void fwd_impl(int b, const float* __restrict__ inputs,
                                         const float* __restrict__ log_A,
                                         const float* __restrict__ log_pi,
                                         const float* __restrict__ log_B,
                                         float* __restrict__ out, Smem& sm) {
  const int tid = threadIdx.x, w = tid >> 6, lane = tid & 63;
  const int g = lane >> 4, q = lane & 15;
  const int cw = w * 64;
  const bool rdl = (q == 0);
  const bool epi = (lane < 16);

  // Static B-operand frags (persistent VGPRs): T[k][f][j] = exp(A[kk][col]).
  f16x8 T[4][8];
#pragma unroll
  for (int k = 0; k < 4; ++k)
#pragma unroll
    for (int f = 0; f < 8; ++f)
#pragma unroll
      for (int j = 0; j < 8; ++j)
        T[k][f][j] =
            (_Float16)__expf(log_A[(size_t)(f * 32 + g * 8 + j) * Q + cw + 16 * k + q]);

  f16x8 Bh[4], Bl[4];
#pragma unroll
  for (int k = 0; k < 4; ++k)
#pragma unroll
    for (int j = 0; j < 8; ++j) {
      const int s = g * 8 + j;
      const float v = (s < S) ? __expf(log_B[(size_t)(cw + 16 * k + q) * S + s]) : 0.f;
      const _Float16 h = (_Float16)v;
      Bh[k][j] = h;
      Bl[k][j] = (_Float16)(v - (float)h);
    }

  const float2* __restrict__ inp2 = (const float2*)(inputs + (size_t)b * L * S);
  const float2* __restrict__ rlast = inp2 + (size_t)(L - 1) * 13;
  float* __restrict__ post_b = out + (size_t)b * L * Q;

  float2 R0[4] = {}, P0[4] = {}, P1[4] = {};
  load_row(inp2, g, rdl, R0);        // row 0 (used immediately)
  load_row(inp2 + 13, g, rdl, P1);   // row 1 (used at t=1)
  load_row(inp2 + 26, g, rdl, P0);   // row 2 (used at t=2)

  f16x8 xh = {}, xl = {};
  f16x8 va[8];
#pragma unroll
  for (int f = 0; f < 8; ++f) va[f] = f16x8{};

  // t = 0
  cvt_row(R0, xh, xl);
  float e[4];
  emit4(xh, xl, Bh, Bl, e);
  float zh[4] = {1.f, 1.f, 1.f, 1.f};
  float rdp_h = 0.f;  // alpha_t = log(zh) + rdp_h, stored one step delayed
  if (epi) {
#pragma unroll
    for (int k = 0; k < 4; ++k) zh[k] = e[k] * __expf(log_pi[cw + 16 * k + lane]);
  }
  if (tid == 0) sm.sh[0] = __logf(zh[0]);  // alpha_0(0)
  lds_barrier();
  float rd_prev = sm.sh[0];
  if (epi) {
    const float sc = __expf(-rd_prev);
#pragma unroll
    for (int k = 0; k < 4; ++k) sm.vb[0][cw + 16 * k + lane] = (_Float16)(zh[k] * sc);
  }
  lds_barrier();

  const float2* pf = inp2 + 3 * 13;  // row t+2 for t=1, advanced by 13/step
  float* pb = post_b + cw + lane;    // row t-1 store base, advanced by Q/step
  int p = 0;

  auto step = [&](int t, float2* Pc) {
    const float rd = sm.sh[p];           // alpha_{t-1}(0)
    if (rdl) read_frags(sm, p, g, va);   // issue ds_reads ASAP
    cvt_row(Pc, xh, xl);                 // row t (in flight since t-2)
    const float2* pu = (t + 2 < L) ? pf : rlast;
    load_row(pu, g, rdl, Pc);            // row t+2
    pf += 13;
    if (epi) {  // delayed store of alpha_{t-1}
#pragma unroll
      for (int k = 0; k < 4; ++k) pb[16 * k] = __logf(zh[k]) + rdp_h;
    }
    pb += Q;
    float ee[4], x[4];
    emit4(xh, xl, Bh, Bl, ee);
    matvec4(va, T, x);
    const float gam = __expf(rd_prev - rd);
    if (epi) {
#pragma unroll
      for (int k = 0; k < 4; ++k) {
        const float z = x[k] * ee[k];
        sm.vb[p ^ 1][cw + 16 * k + lane] = (_Float16)(z * gam);
        zh[k] = z;
      }
      if (tid == 0) sm.sh[p ^ 1] = __logf(zh[0]) + rd_prev;  // alpha_t(0)
    }
    rdp_h = rd_prev;
    rd_prev = rd;
    lds_barrier();
    p ^= 1;
  };

  int t = 1;
  for (; t + 1 < L; t += 2) {  // static parity: P1 odd, P0 even (rule #20)
    step(t, P1);
    step(t + 1, P0);
  }
  step(t, P1);  // t = L-1 (odd)

  // epilogue: final alpha store + exact loglik
  if (epi) {
#pragma unroll
    for (int k = 0; k < 4; ++k) {
      const float a = __logf(zh[k]) + rdp_h;
      pb[16 * k] = a;
      sm.afin[cw + 16 * k + lane] = a;
    }
  }
  lds_barrier();
  if (w == 0) {
    float4 fa = ((const float4*)sm.afin)[lane];
    float m = fmaxf(fmaxf(fa.x, fa.y), fmaxf(fa.z, fa.w));
    m = wave_max64(m);
    float ss = __expf(fa.x - m) + __expf(fa.y - m) + __expf(fa.z - m) + __expf(fa.w - m);
    ss = wave_sum64(ss);
    if (lane == 0) out[POST + b] = __logf(ss) + m;
  }
}

// ---------------- backward ----------------
// MODE 0: beta -> ws (concurrent with fwd). MODE 1: fused RMW post += beta - ll.
template <int MODE>
__device__ __forceinline__ void bwd_impl(int b, const float* __restrict__ inputs,
                                         const float* __restrict__ log_A,
                                         const float* __restrict__ log_B,
                                         float* __restrict__ out,
                                         float* __restrict__ ws, Smem& sm) {
  const int tid = threadIdx.x, w = tid >> 6, lane = tid & 63;
  const int g = lane >> 4, q = lane & 15;
  const int cw = w * 64;
  const bool rdl = (q == 0);
  const bool epi = (lane < 16);

  // bwd matvec is with A (not A^T): T[k][f][j] = exp(log_A[col*Q + kk]).
  f16x8 T[4][8];
#pragma unroll
  for (int k = 0; k < 4; ++k)
#pragma unroll
    for (int f = 0; f < 8; ++f)
#pragma unroll
      for (int j = 0; j < 8; ++j)
        T[k][f][j] =
            (_Float16)__expf(log_A[(size_t)(cw + 16 * k + q) * Q + f * 32 + g * 8 + j]);

  f16x8 Bh[4], Bl[4];
#pragma unroll
  for (int k = 0; k < 4; ++k)
#pragma unroll
    for (int j = 0; j < 8; ++j) {
      const int s = g * 8 + j;
      const float v = (s < S) ? __expf(log_B[(size_t)(cw + 16 * k + q) * S + s]) : 0.f;
      const _Float16 h = (_Float16)v;
      Bh[k][j] = h;
      Bl[k][j] = (_Float16)(v - (float)h);
    }

  const float2* __restrict__ inp2 = (const float2*)(inputs + (size_t)b * L * S);
  float* __restrict__ post_b = out + (size_t)b * L * Q;
  float* __restrict__ ws_b = ws + (size_t)b * L * Q;

  float ll = 0.f, a_h[4] = {0.f, 0.f, 0.f, 0.f};
  if (MODE == 1) {
    ll = out[POST + b];
    if (epi) {
#pragma unroll
      for (int k = 0; k < 4; ++k) a_h[k] = post_b[(size_t)(L - 1) * Q + cw + 16 * k + lane];
    }
  }

  float2 R0[4] = {}, P0[4] = {}, P1[4] = {};
  load_row(inp2 + (size_t)(L - 1) * 13, g, rdl, R0);  // row L-1 (now)
  load_row(inp2 + (size_t)(L - 2) * 13, g, rdl, P0);  // row L-2 (t=L-2, even)
  load_row(inp2 + (size_t)(L - 3) * 13, g, rdl, P1);  // row L-3 (t=L-3, odd)

  f16x8 xh = {}, xl = {};
  f16x8 va[8];
#pragma unroll
  for (int f = 0; f < 8; ++f) va[f] = f16x8{};

  // t = L-1
  cvt_row(R0, xh, xl);
  float e[4];
  emit4(xh, xl, Bh, Bl, e);
  if (tid == 0) sm.sh[0] = __logf(e[0]);  // u_{L-1}(0) = log e_{L-1}(0)
  lds_barrier();
  float rd_prev = sm.sh[0];
  if (epi) {
    const float sc = __expf(-rd_prev);
#pragma unroll
    for (int k = 0; k < 4; ++k) sm.vb[0][cw + 16 * k + lane] = (_Float16)(e[k] * sc);
  }
  float rh[4] = {1.f, 1.f, 1.f, 1.f};  // beta_{L-1} = log(1) + 0
  float rdp_h = 0.f;
  lds_barrier();

  const float2* pf = inp2 + (size_t)(L - 4) * 13;  // row t-2 for t=L-2
  float* wp = ws_b + (size_t)(L - 1) * Q + cw + lane;
  float* pp = post_b + (size_t)(L - 1) * Q + cw + lane;
  int p = 0;

  auto step = [&](int t, float2* Pc) {
    const float rd = sm.sh[p];
    if (rdl) read_frags(sm, p, g, va);
    cvt_row(Pc, xh, xl);  // row t
    const float2* pu = (t >= 2) ? pf : inp2;
    load_row(pu, g, rdl, Pc);  // row t-2
    pf -= 13;
    if (epi) {  // delayed output for row t+1: beta = log(raw) + anchor
      if (MODE == 0) {
#pragma unroll
        for (int k = 0; k < 4; ++k) wp[16 * k] = __logf(rh[k]) + rdp_h;
      } else {
#pragma unroll
        for (int k = 0; k < 4; ++k) pp[16 * k] = a_h[k] + __logf(rh[k]) + rdp_h - ll;
#pragma unroll
        for (int k = 0; k < 4; ++k) a_h[k] = (pp - Q)[16 * k];  // prefetch alpha_t
      }
    }
    wp -= Q;
    pp -= Q;
    float ee[4], x[4];
    emit4(xh, xl, Bh, Bl, ee);
    matvec4(va, T, x);
    const float gam = __expf(rd_prev - rd);
    if (epi) {
#pragma unroll
      for (int k = 0; k < 4; ++k) {
        const float z = x[k] * ee[k];
        sm.vb[p ^ 1][cw + 16 * k + lane] = (_Float16)(z * gam);
        rh[k] = x[k];
      }
      if (tid == 0) sm.sh[p ^ 1] = __logf(x[0] * ee[0]) + rd_prev;  // u_t(0)
    }
    rdp_h = rd_prev;
    rd_prev = rd;
    lds_barrier();
    p ^= 1;
  };

  int t = L - 2;
  for (; t >= 1; t -= 2) {  // static parity: P0 even, P1 odd (rule #20)
    step(t, P0);
    step(t - 1, P1);
  }
  step(0, P0);  // t = 0 (even)

  // epilogue: row 0
  if (epi) {
    if (MODE == 0) {
#pragma unroll
      for (int k = 0; k < 4; ++k) wp[16 * k] = __logf(rh[k]) + rdp_h;
    } else {
#pragma unroll
      for (int k = 0; k < 4; ++k) pp[16 * k] = a_h[k] + __logf(rh[k]) + rdp_h - ll;
    }
  }
}

// ---------------- kernels ----------------
__global__ __launch_bounds__(256, 1)
void hmm_fwdbwd(const float* __restrict__ inputs, const float* __restrict__ log_A,
                const float* __restrict__ log_pi, const float* __restrict__ log_B,
                float* __restrict__ out, float* __restrict__ ws) {
  __shared__ Smem sm;
  if (blockIdx.x < B) fwd_impl(blockIdx.x, inputs, log_A, log_pi, log_B, out, sm);
  else                bwd_impl<0>(blockIdx.x - B, inputs, log_A, log_B, out, ws, sm);
}

__global__ __launch_bounds__(256)
void hmm_combine(const float* __restrict__ ws, float* __restrict__ out) {
  const size_t idx = (size_t)blockIdx.x * 256 + threadIdx.x;  // float4 index
  const int b = (int)(idx >> 17);  // L*Q/4 = 131072 float4 per batch
  const float ll = out[POST + b];
  float4 a = ((const float4*)out)[idx];
  const float4 be = ((const float4*)ws)[idx];
  a.x += be.x - ll;
  a.y += be.y - ll;
  a.z += be.z - ll;
  a.w += be.w - ll;
  ((float4*)out)[idx] = a;
}

__global__ __launch_bounds__(256, 1)
void hmm_fwd_only(const float* __restrict__ inputs, const float* __restrict__ log_A,
                  const float* __restrict__ log_pi, const float* __restrict__ log_B,
                  float* __restrict__ out) {
  __shared__ Smem sm;
  fwd_impl(blockIdx.x, inputs, log_A, log_pi, log_B, out, sm);
}

__global__ __launch_bounds__(256, 1)
void hmm_bwd_fused(const float* __restrict__ inputs, const float* __restrict__ log_A,
                   const float* __restrict__ log_B, float* __restrict__ out) {
  __shared__ Smem sm;
  bwd_impl<1>(blockIdx.x, inputs, log_A, log_B, out, nullptr, sm);
}

}  // namespace

extern "C" void kernel_launch(void* const* d_in, const int* in_sizes, int n_in,
                              void* d_out, int out_size, void* d_ws, size_t ws_size,
                              hipStream_t stream) {
  const float* inputs = (const float*)d_in[0];
  const float* log_A  = (const float*)d_in[1];
  const float* log_pi = (const float*)d_in[2];
  const float* log_B  = (const float*)d_in[3];
  float* out = (float*)d_out;
  float* ws  = (float*)d_ws;

  if (ws_size >= POST * sizeof(float)) {
    hipLaunchKernelGGL(hmm_fwdbwd, dim3(2 * B), dim3(256), 0, stream,
                       inputs, log_A, log_pi, log_B, out, ws);
    hipLaunchKernelGGL(hmm_combine, dim3((unsigned)(POST / 4 / 256)), dim3(256), 0, stream,
                       ws, out);
  } else {
    hipLaunchKernelGGL(hmm_fwd_only, dim3(B), dim3(256), 0, stream,
                       inputs, log_A, log_pi, log_B, out);
    hipLaunchKernelGGL(hmm_bwd_fused, dim3(B), dim3(256), 0, stream,
                       inputs, log_A, log_B, out);
  }
}

// Round 4
// 1600.700 us; speedup vs baseline: 1.1976x; 1.1976x over previous
//
#include <hip/hip_runtime.h>

namespace {

constexpr int B = 64;
constexpr int L = 2048;
constexpr int Q = 256;
constexpr int S = 26;
constexpr float EPS = 1e-16f;
constexpr size_t POST = (size_t)B * L * Q;  // loglik offset in d_out

typedef _Float16 h2 __attribute__((ext_vector_type(2)));
typedef _Float16 f16x8 __attribute__((ext_vector_type(8)));
typedef float f32x4 __attribute__((ext_vector_type(4)));

#define MFMA16(a, b, c) __builtin_amdgcn_mfma_f32_16x16x32_f16((a), (b), (c), 0, 0, 0)

struct Smem {
  alignas(16) _Float16 vb[2][Q];     // scaled linear recursion vector (f16), dbuf
  alignas(16) _Float16 rowh[2][32];  // staged input row, f16 hi part (padded 26->32)
  alignas(16) _Float16 rowl[2][32];  // f16 lo residual part
  float sh[2];                       // state-0 anchor broadcast, dbuf
  alignas(16) float afin[Q];         // final alpha for exact loglik
};

// LDS-only rendezvous: drain lgkm (covers LDS reads AND writes) but leave
// global loads/stores in flight across the barrier. __syncthreads would
// drain vmcnt(0) too, exposing store-ack + staged-load latency every step.
__device__ __forceinline__ void lds_barrier() {
  asm volatile("s_waitcnt lgkmcnt(0)\n\ts_barrier" ::: "memory");
}

__device__ __forceinline__ float wave_max64(float x) {
#pragma unroll
  for (int off = 32; off > 0; off >>= 1) x = fmaxf(x, __shfl_xor(x, off, 64));
  return x;
}
__device__ __forceinline__ float wave_sum64(float x) {
#pragma unroll
  for (int off = 32; off > 0; off >>= 1) x += __shfl_xor(x, off, 64);
  return x;
}

// Emission B-operand frags: expB^T[s][state], hi/lo split for ~f32 accuracy.
// B-frag layout (16x16x32): lane l holds B[(l>>4)*8 + j][l&15], j=0..7.
__device__ __forceinline__ void load_emit_frags(const float* __restrict__ log_B,
                                                int c0, int c1, int g, int q,
                                                f16x8& Bh0, f16x8& Bl0,
                                                f16x8& Bh1, f16x8& Bl1) {
#pragma unroll
  for (int j = 0; j < 8; ++j) {
    const int s = g * 8 + j;
    const float v0 = (s < S) ? __expf(log_B[(size_t)(c0 + q) * S + s]) : 0.f;
    const float v1 = (s < S) ? __expf(log_B[(size_t)(c1 + q) * S + s]) : 0.f;
    const _Float16 h0 = (_Float16)v0, h1 = (_Float16)v1;
    Bh0[j] = h0; Bl0[j] = (_Float16)(v0 - (float)h0);
    Bh1[j] = h1; Bl1[j] = (_Float16)(v1 - (float)h1);
  }
}

// Stage one input row (26 f32) into LDS as f16 hi + f16 residual, padded to
// 32. Called by wave 0, lanes 0..15 (lanes 13..15 write zero pad). The f32
// to hi/lo conversion is paid ONCE here, not per-step on every wave.
__device__ __forceinline__ void stage_row(Smem& sm, int buf, int lane, float2 gg) {
  _Float16 ah = (_Float16)0.f, bh = (_Float16)0.f;
  _Float16 al = (_Float16)0.f, bl = (_Float16)0.f;
  if (lane < 13) {
    ah = (_Float16)gg.x; bh = (_Float16)gg.y;
    al = (_Float16)(gg.x - (float)ah);
    bl = (_Float16)(gg.y - (float)bh);
  }
  ((h2*)sm.rowh[buf])[lane] = h2{ah, bh};
  ((h2*)sm.rowl[buf])[lane] = h2{al, bl};
}

// emit = (xh+xl) . (Bh+Bl) ~= xh*Bl + xl*Bh + xh*Bh  (3-term, ~f32 accurate)
__device__ __forceinline__ void emit_mfma(const f16x8& xh, const f16x8& xl,
                                          const f16x8& Bh0, const f16x8& Bl0,
                                          const f16x8& Bh1, const f16x8& Bl1,
                                          f32x4& E0, f32x4& E1) {
  const f32x4 Z = {0.f, 0.f, 0.f, 0.f};
  E0 = MFMA16(xh, Bl0, Z);
  E0 = MFMA16(xl, Bh0, E0);
  E0 = MFMA16(xh, Bh0, E0);
  E1 = MFMA16(xh, Bl1, Z);
  E1 = MFMA16(xl, Bh1, E1);
  E1 = MFMA16(xh, Bh1, E1);
}

// x = v^T * T for this wave's two 16-state column tiles; K=256 as 8 frags,
// two 4-deep chains per tile for ILP. Only D row 0 (reg 0, lanes 0..15) is
// meaningful; garbage in A rows 1..15 cannot reach row 0.
__device__ __forceinline__ void matvec_mfma(const f16x8* va, const f16x8* T0,
                                            const f16x8* T1, float& x0, float& x1) {
  const f32x4 Z = {0.f, 0.f, 0.f, 0.f};
  f32x4 X0a = MFMA16(va[0], T0[0], Z);
  f32x4 X1a = MFMA16(va[0], T1[0], Z);
  f32x4 X0b = MFMA16(va[4], T0[4], Z);
  f32x4 X1b = MFMA16(va[4], T1[4], Z);
#pragma unroll
  for (int f = 1; f < 4; ++f) {
    X0a = MFMA16(va[f], T0[f], X0a);
    X1a = MFMA16(va[f], T1[f], X1a);
    X0b = MFMA16(va[f + 4], T0[f + 4], X0b);
    X1b = MFMA16(va[f + 4], T1[f + 4], X1b);
  }
  x0 = X0a[0] + X0b[0];
  x1 = X1a[0] + X1b[0];
}

// Sparse frag reads: only lanes with (lane&15)==0 carry A-operand data
// (row 0 of the 16x32 A frag). Exec-masked -> 4 active lanes per ds_read.
__device__ __forceinline__ void read_frags(Smem& sm, int p, int g,
                                           f16x8& xh, f16x8& xl, f16x8* va) {
  xh = *(const f16x8*)(sm.rowh[p] + g * 8);
  xl = *(const f16x8*)(sm.rowl[p] + g * 8);
  const _Float16* vbp = sm.vb[p];
#pragma unroll
  for (int f = 0; f < 8; ++f) va[f] = *(const f16x8*)(vbp + f * 32 + g * 8);
}

// ---------------- forward ----------------
// Linear-space recursion with one-step-stale state-0 anchor; matvec+emission
// on the matrix pipe. Staging is 2 rows deep so wave 0's ds_write at the top
// of step t uses a load issued during step t-1 (vmcnt long satisfied).
__device__ __forceinline__ void fwd_impl(int b, const float* __restrict__ inputs,
                                         const float* __restrict__ log_A,
                                         const float* __restrict__ log_pi,
                                         const float* __restrict__ log_B,
                                         float* __restrict__ out, Smem& sm) {
  const int tid = threadIdx.x, w = tid >> 6, lane = tid & 63;
  const int g = lane >> 4, q = lane & 15;
  const int c0 = w * 32, c1 = c0 + 16;
  const bool rdl = (q == 0);
  const bool epi = (lane < 16);
  const bool stg = (w == 0) && (lane < 16);

  // Static B-operand frags (persistent in VGPRs): T[k][c] = exp(log_A[k*Q+c]).
  f16x8 T0[8], T1[8];
#pragma unroll
  for (int f = 0; f < 8; ++f) {
#pragma unroll
    for (int j = 0; j < 8; ++j) {
      const int k = f * 32 + g * 8 + j;
      T0[f][j] = (_Float16)__expf(log_A[(size_t)k * Q + c0 + q]);
      T1[f][j] = (_Float16)__expf(log_A[(size_t)k * Q + c1 + q]);
    }
  }
  f16x8 Bh0, Bl0, Bh1, Bl1;
  load_emit_frags(log_B, c0, c1, g, q, Bh0, Bl0, Bh1, Bl1);

  const float2* __restrict__ inp2 = (const float2*)(inputs + (size_t)b * L * S);
  float* __restrict__ post_b = out + (size_t)b * L * Q;

  // ---- init: stage rows 0 (buf1) and 1 (buf0); hold row 2 in regs ----
  float2 gHold = {0.f, 0.f};
  if (stg) {
    float2 g0 = {0.f, 0.f}, g1 = {0.f, 0.f};
    if (lane < 13) {
      g0 = inp2[lane];
      g1 = inp2[13 + lane];
      gHold = inp2[26 + lane];
    }
    stage_row(sm, 1, lane, g0);
    stage_row(sm, 0, lane, g1);
  }
  __syncthreads();

  f16x8 xh = {}, xl = {};
  f16x8 va[8];
#pragma unroll
  for (int f = 0; f < 8; ++f) va[f] = f16x8{};

  // t = 0
  if (rdl) {
    xh = *(const f16x8*)(sm.rowh[1] + g * 8);
    xl = *(const f16x8*)(sm.rowl[1] + g * 8);
  }
  f32x4 E0, E1;
  emit_mfma(xh, xl, Bh0, Bl0, Bh1, Bl1, E0, E1);
  float zh0 = 1.f, zh1 = 1.f, rdp_h = 0.f;  // alpha_t = log(zh)+rdp_h, deferred
  if (epi) {
    zh0 = (E0[0] + EPS) * __expf(log_pi[c0 + lane]);
    zh1 = (E1[0] + EPS) * __expf(log_pi[c1 + lane]);
  }
  if (tid == 0) sm.sh[0] = __logf(zh0);  // alpha_0(0)
  __syncthreads();
  float rd_prev = sm.sh[0];
  if (epi) {
    const float sc = __expf(-rd_prev);
    sm.vb[0][c0 + lane] = (_Float16)(zh0 * sc);
    sm.vb[0][c1 + lane] = (_Float16)(zh1 * sc);
  }
  __syncthreads();

  int p = 0;
  for (int t = 1; t < L; ++t) {
    // stage row t+1 from regs held since step t-1 (no vmcnt stall)
    if (stg) stage_row(sm, p ^ 1, lane, gHold);
    const float rd = sm.sh[p];  // alpha_{t-1}(0)
    // issue load of row t+2
    float2 gN = gHold;
    const int tt = (t + 2 < L) ? t + 2 : L - 1;
    if (w == 0 && lane < 13) gN = inp2[(size_t)tt * 13 + lane];
    // delayed store of alpha_{t-1} (log off the critical path)
    if (epi) {
      const float a0 = __logf(zh0) + rdp_h;
      const float a1 = __logf(zh1) + rdp_h;
      post_b[(size_t)(t - 1) * Q + c0 + lane] = a0;
      post_b[(size_t)(t - 1) * Q + c1 + lane] = a1;
    }
    if (rdl) read_frags(sm, p, g, xh, xl, va);
    f32x4 E0_, E1_;
    emit_mfma(xh, xl, Bh0, Bl0, Bh1, Bl1, E0_, E1_);
    float x0, x1;
    matvec_mfma(va, T0, T1, x0, x1);
    const float gam = __expf(rd_prev - rd);
    if (epi) {
      const float e0 = E0_[0] + EPS, e1 = E1_[0] + EPS;
      const float z0 = x0 * e0, z1 = x1 * e1;
      sm.vb[p ^ 1][c0 + lane] = (_Float16)(z0 * gam);
      sm.vb[p ^ 1][c1 + lane] = (_Float16)(z1 * gam);
      if (tid == 0) sm.sh[p ^ 1] = __logf(z0) + rd_prev;  // alpha_t(0)
      zh0 = z0; zh1 = z1;
    }
    gHold = gN;
    rdp_h = rd_prev;
    rd_prev = rd;
    lds_barrier();
    p ^= 1;
  }

  // epilogue: final alpha store + exact loglik
  if (epi) {
    const float a0 = __logf(zh0) + rdp_h;
    const float a1 = __logf(zh1) + rdp_h;
    post_b[(size_t)(L - 1) * Q + c0 + lane] = a0;
    post_b[(size_t)(L - 1) * Q + c1 + lane] = a1;
    sm.afin[c0 + lane] = a0;
    sm.afin[c1 + lane] = a1;
  }
  __syncthreads();
  if (w == 0) {
    float4 fa = ((const float4*)sm.afin)[lane];
    float m = fmaxf(fmaxf(fa.x, fa.y), fmaxf(fa.z, fa.w));
    m = wave_max64(m);
    float ss = __expf(fa.x - m) + __expf(fa.y - m) + __expf(fa.z - m) + __expf(fa.w - m);
    ss = wave_sum64(ss);
    if (lane == 0) out[POST + b] = __logf(ss) + m;
  }
}

// ---------------- backward ----------------
// MODE 0: beta -> ws (concurrent with fwd). MODE 1: fused RMW post += beta - ll.
template <int MODE>
__device__ __forceinline__ void bwd_impl(int b, const float* __restrict__ inputs,
                                         const float* __restrict__ log_A,
                                         const float* __restrict__ log_B,
                                         float* __restrict__ out,
                                         float* __restrict__ ws, Smem& sm) {
  const int tid = threadIdx.x, w = tid >> 6, lane = tid & 63;
  const int g = lane >> 4, q = lane & 15;
  const int c0 = w * 32, c1 = c0 + 16;
  const bool rdl = (q == 0);
  const bool epi = (lane < 16);
  const bool stg = (w == 0) && (lane < 16);

  // bwd matvec is with A (not A^T): T[k][c] = exp(log_A[c*Q + k]).
  f16x8 T0[8], T1[8];
#pragma unroll
  for (int f = 0; f < 8; ++f) {
#pragma unroll
    for (int j = 0; j < 8; ++j) {
      const int k = f * 32 + g * 8 + j;
      T0[f][j] = (_Float16)__expf(log_A[(size_t)(c0 + q) * Q + k]);
      T1[f][j] = (_Float16)__expf(log_A[(size_t)(c1 + q) * Q + k]);
    }
  }
  f16x8 Bh0, Bl0, Bh1, Bl1;
  load_emit_frags(log_B, c0, c1, g, q, Bh0, Bl0, Bh1, Bl1);

  const float2* __restrict__ inp2 = (const float2*)(inputs + (size_t)b * L * S);
  float* __restrict__ post_b = out + (size_t)b * L * Q;
  float* __restrict__ ws_b = ws + (size_t)b * L * Q;

  float ll = 0.f, a_h0 = 0.f, a_h1 = 0.f;
  if (MODE == 1) {
    ll = out[POST + b];
    if (epi) {
      a_h0 = post_b[(size_t)(L - 1) * Q + c0 + lane];
      a_h1 = post_b[(size_t)(L - 1) * Q + c1 + lane];
    }
  }

  // ---- init: stage rows L-1 (buf1), L-2 (buf0); hold row L-3 in regs ----
  float2 gHold = {0.f, 0.f};
  if (stg) {
    float2 g0 = {0.f, 0.f}, g1 = {0.f, 0.f};
    if (lane < 13) {
      g0 = inp2[(size_t)(L - 1) * 13 + lane];
      g1 = inp2[(size_t)(L - 2) * 13 + lane];
      gHold = inp2[(size_t)(L - 3) * 13 + lane];
    }
    stage_row(sm, 1, lane, g0);
    stage_row(sm, 0, lane, g1);
  }
  __syncthreads();

  f16x8 xh = {}, xl = {};
  f16x8 va[8];
#pragma unroll
  for (int f = 0; f < 8; ++f) va[f] = f16x8{};

  // t = L-1
  if (rdl) {
    xh = *(const f16x8*)(sm.rowh[1] + g * 8);
    xl = *(const f16x8*)(sm.rowl[1] + g * 8);
  }
  f32x4 E0, E1;
  emit_mfma(xh, xl, Bh0, Bl0, Bh1, Bl1, E0, E1);
  float e0i = 1.f, e1i = 1.f;
  if (epi) { e0i = E0[0] + EPS; e1i = E1[0] + EPS; }
  if (tid == 0) sm.sh[0] = __logf(e0i);  // u_{L-1}(0)
  __syncthreads();
  float rd_prev = sm.sh[0];
  if (epi) {
    const float sc = __expf(-rd_prev);
    sm.vb[0][c0 + lane] = (_Float16)(e0i * sc);
    sm.vb[0][c1 + lane] = (_Float16)(e1i * sc);
  }
  float rh0 = 1.f, rh1 = 1.f, rdp_h = 0.f;  // beta_{L-1} = 0
  __syncthreads();

  int p = 0;
  for (int t = L - 2; t >= 0; --t) {
    // stage row t-1 from regs held since last step
    if (stg) stage_row(sm, p ^ 1, lane, gHold);
    const float rd = sm.sh[p];
    // issue load of row t-2
    float2 gN = gHold;
    const int tt = (t >= 2) ? t - 2 : 0;
    if (w == 0 && lane < 13) gN = inp2[(size_t)tt * 13 + lane];
    if (epi) {  // delayed output for row t+1: beta = log(raw) + anchor
      const float b0 = __logf(rh0) + rdp_h;
      const float b1 = __logf(rh1) + rdp_h;
      if (MODE == 0) {
        ws_b[(size_t)(t + 1) * Q + c0 + lane] = b0;
        ws_b[(size_t)(t + 1) * Q + c1 + lane] = b1;
      } else {
        post_b[(size_t)(t + 1) * Q + c0 + lane] = a_h0 + b0 - ll;
        post_b[(size_t)(t + 1) * Q + c1 + lane] = a_h1 + b1 - ll;
        a_h0 = post_b[(size_t)t * Q + c0 + lane];  // prefetch alpha_t
        a_h1 = post_b[(size_t)t * Q + c1 + lane];
      }
    }
    if (rdl) read_frags(sm, p, g, xh, xl, va);
    f32x4 E0_, E1_;
    emit_mfma(xh, xl, Bh0, Bl0, Bh1, Bl1, E0_, E1_);
    float r0, r1;
    matvec_mfma(va, T0, T1, r0, r1);
    const float gam = __expf(rd_prev - rd);
    if (epi) {
      const float e0 = E0_[0] + EPS, e1 = E1_[0] + EPS;
      const float z0 = r0 * e0, z1 = r1 * e1;
      sm.vb[p ^ 1][c0 + lane] = (_Float16)(z0 * gam);
      sm.vb[p ^ 1][c1 + lane] = (_Float16)(z1 * gam);
      if (tid == 0) sm.sh[p ^ 1] = __logf(z0) + rd_prev;  // u_t(0)
      rh0 = r0; rh1 = r1;
    }
    gHold = gN;
    rdp_h = rd_prev;
    rd_prev = rd;
    lds_barrier();
    p ^= 1;
  }

  // epilogue: row 0
  if (epi) {
    const float b0 = __logf(rh0) + rdp_h;
    const float b1 = __logf(rh1) + rdp_h;
    if (MODE == 0) {
      ws_b[c0 + lane] = b0;
      ws_b[c1 + lane] = b1;
    } else {
      post_b[c0 + lane] = a_h0 + b0 - ll;
      post_b[c1 + lane] = a_h1 + b1 - ll;
    }
  }
}

// ---------------- kernels ----------------
__global__ __launch_bounds__(512, 2)
void hmm_fwdbwd(const float* __restrict__ inputs, const float* __restrict__ log_A,
                const float* __restrict__ log_pi, const float* __restrict__ log_B,
                float* __restrict__ out, float* __restrict__ ws) {
  __shared__ Smem sm;
  if (blockIdx.x < B) fwd_impl(blockIdx.x, inputs, log_A, log_pi, log_B, out, sm);
  else                bwd_impl<0>(blockIdx.x - B, inputs, log_A, log_B, out, ws, sm);
}

__global__ __launch_bounds__(256)
void hmm_combine(const float* __restrict__ ws, float* __restrict__ out) {
  const size_t idx = (size_t)blockIdx.x * 256 + threadIdx.x;  // float4 index
  const int b = (int)(idx >> 17);  // L*Q/4 = 131072 float4 per batch
  const float ll = out[POST + b];
  float4 a = ((const float4*)out)[idx];
  const float4 be = ((const float4*)ws)[idx];
  a.x += be.x - ll;
  a.y += be.y - ll;
  a.z += be.z - ll;
  a.w += be.w - ll;
  ((float4*)out)[idx] = a;
}

__global__ __launch_bounds__(512, 2)
void hmm_fwd_only(const float* __restrict__ inputs, const float* __restrict__ log_A,
                  const float* __restrict__ log_pi, const float* __restrict__ log_B,
                  float* __restrict__ out) {
  __shared__ Smem sm;
  fwd_impl(blockIdx.x, inputs, log_A, log_pi, log_B, out, sm);
}

__global__ __launch_bounds__(512, 2)
void hmm_bwd_fused(const float* __restrict__ inputs, const float* __restrict__ log_A,
                   const float* __restrict__ log_B, float* __restrict__ out) {
  __shared__ Smem sm;
  bwd_impl<1>(blockIdx.x, inputs, log_A, log_B, out, nullptr, sm);
}

}  // namespace

extern "C" void kernel_launch(void* const* d_in, const int* in_sizes, int n_in,
                              void* d_out, int out_size, void* d_ws, size_t ws_size,
                              hipStream_t stream) {
  const float* inputs = (const float*)d_in[0];
  const float* log_A  = (const float*)d_in[1];
  const float* log_pi = (const float*)d_in[2];
  const float* log_B  = (const float*)d_in[3];
  float* out = (float*)d_out;
  float* ws  = (float*)d_ws;

  if (ws_size >= POST * sizeof(float)) {
    hipLaunchKernelGGL(hmm_fwdbwd, dim3(2 * B), dim3(512), 0, stream,
                       inputs, log_A, log_pi, log_B, out, ws);
    hipLaunchKernelGGL(hmm_combine, dim3((unsigned)(POST / 4 / 256)), dim3(256), 0, stream,
                       ws, out);
  } else {
    hipLaunchKernelGGL(hmm_fwd_only, dim3(B), dim3(512), 0, stream,
                       inputs, log_A, log_pi, log_B, out);
    hipLaunchKernelGGL(hmm_bwd_fused, dim3(B), dim3(512), 0, stream,
                       inputs, log_A, log_B, out);
  }
}